// Round 20
// baseline (80.594 us; speedup 1.0000x reference)
//
#include <hip/hip_runtime.h>

#define N_NODES 100000
#define NP 100096            // NB*128 padded node count
#define N_EDGES 3200000
#define NB 782               // buckets of 128 nodes
#define NBP 1024             // padded bins for scan
#define NHR 256              // binning blocks / regions (256*12500 = 3.2M exact)
#define EPB (N_EDGES / NHR)  // 12500 edges per region (mult of 4)
#define RS 14848             // region stride (words): 12500 + 3*782 = 14846 max
#define BSB 512              // binning block threads
#define CAP 6144             // regroup stage capacity (padded words)
#define CAPO 5120            // regroup out capacity (quad-padded per-node segs)
#define CSRS 5120            // csr words per bucket (mult of 4)
#define SENT 128u            // run-pad sentinel: low byte 128

typedef unsigned char u8;

// ---------- binning: per-block LDS counting sort, padded runs, linear flush ----
// binned region-major; runs 4-word aligned; pads hold SENT.
// packed = (src<<8)|(dst&127). runinfoT[b*NHR+r] = off | (nq<<16), nq quads.
__global__ __launch_bounds__(BSB) void k_bin3(const int* __restrict__ src,
                                              const int* __restrict__ dst,
                                              unsigned* __restrict__ binned,
                                              unsigned* __restrict__ runinfoT) {
    __shared__ int hist[NBP];
    __shared__ int scanv[NBP];
    __shared__ int sh[BSB];
    __shared__ alignas(16) unsigned stage[RS];
    int t = threadIdx.x, blk = blockIdx.x;
    for (int i = t; i < NBP; i += BSB) hist[i] = 0;
    for (int i = t; i < RS; i += BSB) stage[i] = SENT;
    __syncthreads();
    int base = blk * EPB;
    for (int i = t * 4; i < EPB; i += BSB * 4) {
        int4 d = *(const int4*)(dst + base + i);
        atomicAdd(&hist[d.x >> 7], 1);
        atomicAdd(&hist[d.y >> 7], 1);
        atomicAdd(&hist[d.z >> 7], 1);
        atomicAdd(&hist[d.w >> 7], 1);
    }
    __syncthreads();
    int c0 = hist[2 * t], c1 = hist[2 * t + 1];
    int p0 = (c0 + 3) & ~3, p1 = (c1 + 3) & ~3;
    int v = p0 + p1;
    sh[t] = v;
    __syncthreads();
    for (int off = 1; off < BSB; off <<= 1) {
        int u = (t >= off) ? sh[t - off] : 0;
        __syncthreads();
        sh[t] += u;
        __syncthreads();
    }
    int excl = sh[t] - v;
    scanv[2 * t] = excl;
    scanv[2 * t + 1] = excl + p0;
    __syncthreads();
    int padTot = sh[BSB - 1];
    for (int b = t; b < NB; b += BSB)
        runinfoT[(size_t)b * NHR + blk] =
            (unsigned)scanv[b] | ((unsigned)((hist[b] + 3) >> 2) << 16);
    __syncthreads();
    for (int i = t * 4; i < EPB; i += BSB * 4) {
        int4 s4 = *(const int4*)(src + base + i);
        int4 d4 = *(const int4*)(dst + base + i);
        int p;
        p = atomicAdd(&scanv[d4.x >> 7], 1);
        stage[p] = ((unsigned)s4.x << 8) | (unsigned)(d4.x & 127);
        p = atomicAdd(&scanv[d4.y >> 7], 1);
        stage[p] = ((unsigned)s4.y << 8) | (unsigned)(d4.y & 127);
        p = atomicAdd(&scanv[d4.z >> 7], 1);
        stage[p] = ((unsigned)s4.z << 8) | (unsigned)(d4.z & 127);
        p = atomicAdd(&scanv[d4.w >> 7], 1);
        stage[p] = ((unsigned)s4.w << 8) | (unsigned)(d4.w & 127);
    }
    __syncthreads();
    for (int i = t * 4; i < padTot; i += BSB * 4)
        *(int4*)(binned + (size_t)blk * RS + i) = *(const int4*)(stage + i);
}

// ---------- regroup v2: fused copy+count, 4-rep counters/cursors ----------
// Each node's csr segment starts at a quad boundary; pad slots = 0xFFFFFFFF.
// Per-node segment = concat of 4 rep sub-segments (order within seg arbitrary).
__global__ __launch_bounds__(256) void k_regroup(
        const unsigned* __restrict__ binned, const unsigned* __restrict__ runinfoT,
        const float* __restrict__ x, unsigned* __restrict__ csr,
        int* __restrict__ startv, int* __restrict__ lenv,
        float* __restrict__ dinv, float* __restrict__ s) {
    __shared__ unsigned rinfo[NHR];
    __shared__ int pref[NHR];
    __shared__ int sh[256];
    __shared__ alignas(16) unsigned stage[CAP];
    __shared__ unsigned outA[CAPO];
    __shared__ int cnt[4][128];
    __shared__ int base4[4][128];
    __shared__ int excl4[128];
    __shared__ int fillTotSh;
    int t = threadIdx.x, b = blockIdx.x;
    rinfo[t] = runinfoT[(size_t)b * NHR + t];  // NHR == 256 == blockDim
    for (int i = t; i < 4 * 128; i += 256) ((int*)cnt)[i] = 0;
    for (int i = t; i < CAPO; i += 256) outA[i] = 0xFFFFFFFFu;
    __syncthreads();
    // scan padded run lengths (4*nq), one entry per thread
    int vv = 4 * (int)(rinfo[t] >> 16);
    sh[t] = vv;
    __syncthreads();
    for (int off = 1; off < 256; off <<= 1) {
        int u = (t >= off) ? sh[t - off] : 0;
        __syncthreads();
        sh[t] += u;
        __syncthreads();
    }
    pref[t] = sh[t] - vv;
    __syncthreads();
    // fused copy + count: 4-lane groups; run r uses rep = r&3 (r ≡ g mod 64)
    int g = t >> 2, lane = t & 3, rep = g & 3;
    for (int r = g; r < NHR; r += 64) {
        unsigned ri = rinfo[r];
        int off = (int)(ri & 0xFFFFu), nq = (int)(ri >> 16);
        int bs = pref[r];
        if (bs + 4 * nq > CAP) continue;  // impossible-margin guard
        const uint4* p = (const uint4*)(binned + (size_t)r * RS + off);
        for (int j = lane; j < nq; j += 4) {
            uint4 w = p[j];
            *(uint4*)(&stage[bs + 4 * j]) = make_uint4(w.x, w.y, w.z, w.w);
            if ((w.x & 255u) != 128u) atomicAdd(&cnt[rep][w.x & 127], 1);
            if ((w.y & 255u) != 128u) atomicAdd(&cnt[rep][w.y & 127], 1);
            if ((w.z & 255u) != 128u) atomicAdd(&cnt[rep][w.z & 127], 1);
            if ((w.w & 255u) != 128u) atomicAdd(&cnt[rep][w.w & 127], 1);
        }
    }
    __syncthreads();
    // per-node totals, quad-padded scan over 128 nodes
    int tot = 0;
    if (t < 128) {
#pragma unroll
        for (int c = 0; c < 4; ++c) tot += cnt[c][t];
        sh[t] = (tot + 3) & ~3;
    }
    __syncthreads();
    for (int off = 1; off < 128; off <<= 1) {
        int u = (t >= off && t < 128) ? sh[t - off] : 0;
        __syncthreads();
        if (t < 128) sh[t] += u;
        __syncthreads();
    }
    if (t < 128) {
        int pc = (tot + 3) & ~3;
        int e = sh[t] - pc;
        excl4[t] = e;
        int running = e;
#pragma unroll
        for (int c = 0; c < 4; ++c) {
            base4[c][t] = running;
            running += cnt[c][t];
        }
        if (t == 127) fillTotSh = e + pc;
    }
    __syncthreads();
    // scatter: SAME run decomposition as copy (rep consistency), stage -> outA
    for (int r = g; r < NHR; r += 64) {
        unsigned ri = rinfo[r];
        int nq = (int)(ri >> 16);
        int bs = pref[r];
        if (bs + 4 * nq > CAP) continue;
        for (int j = lane; j < nq; j += 4) {
            uint4 w = *(const uint4*)(&stage[bs + 4 * j]);
            if ((w.x & 255u) != 128u) {
                int pos = atomicAdd(&base4[rep][w.x & 127], 1);
                if (pos < CAPO) outA[pos] = w.x >> 8;
            }
            if ((w.y & 255u) != 128u) {
                int pos = atomicAdd(&base4[rep][w.y & 127], 1);
                if (pos < CAPO) outA[pos] = w.y >> 8;
            }
            if ((w.z & 255u) != 128u) {
                int pos = atomicAdd(&base4[rep][w.z & 127], 1);
                if (pos < CAPO) outA[pos] = w.z >> 8;
            }
            if ((w.w & 255u) != 128u) {
                int pos = atomicAdd(&base4[rep][w.w & 127], 1);
                if (pos < CAPO) outA[pos] = w.w >> 8;
            }
        }
    }
    __syncthreads();
    int fillTot = fillTotSh;
    if (fillTot > CAPO) fillTot = CAPO;
    for (int i = t; i < fillTot; i += 256)
        csr[(size_t)b * CSRS + i] = outA[i];
    if (t < 128) {
        int node = b * 128 + t;
        if (node < N_NODES) {
            float di = rsqrtf((float)(tot + 1));  // +1 self-loop
            dinv[node] = di;
            s[node] = di * x[node];
            startv[node] = b * CSRS + excl4[t];  // quad-aligned
            lenv[node] = tot;
        }
    }
}

// ---------- s1 + MLP fused: 4-lane group per node, uint4 coalesced CSR ----------
__global__ __launch_bounds__(256) void k_s1c(const unsigned* __restrict__ csr,
                                             const int* __restrict__ startv,
                                             const int* __restrict__ lenv,
                                             const float* __restrict__ dinv,
                                             const float* __restrict__ s,
                                             const float* __restrict__ W1,
                                             const float* __restrict__ b1,
                                             const float* __restrict__ W2,
                                             float2* __restrict__ z) {
    int t = threadIdx.x;
    int v = blockIdx.x * 64 + (t >> 2);
    int lane = t & 3;
    if (v >= N_NODES) return;
    int st = startv[v], d = lenv[v];
    int nq = (d + 3) >> 2;
    const uint4* p = (const uint4*)(csr + st);
    float acc = 0.f;
    for (int j = lane; j < nq; j += 4) {
        uint4 w = p[j];
        float f0 = (w.x < N_NODES) ? s[w.x] : 0.f;
        float f1 = (w.y < N_NODES) ? s[w.y] : 0.f;
        float f2 = (w.z < N_NODES) ? s[w.z] : 0.f;
        float f3 = (w.w < N_NODES) ? s[w.w] : 0.f;
        acc += (f0 + f1) + (f2 + f3);
    }
    acc += __shfl_xor(acc, 1);
    acc += __shfl_xor(acc, 2);
    if (lane == 0) {
        float di = dinv[v];
        float a = di * (acc + s[v]);  // self-loop term
        float z0 = 0.f, z1 = 0.f;
#pragma unroll
        for (int f = 0; f < 16; ++f) {
            float h = fmaxf(a * W1[f] + b1[f], 0.f);
            z0 += h * W2[2 * f + 0];
            z1 += h * W2[2 * f + 1];
        }
        z[v] = make_float2(di * z0, di * z1);
    }
}

// ---------- s2 + epilogue fused: 4-lane group per node, float2 gathers ----------
__global__ __launch_bounds__(256) void k_s2c(const unsigned* __restrict__ csr,
                                             const int* __restrict__ startv,
                                             const int* __restrict__ lenv,
                                             const float* __restrict__ dinv,
                                             const float2* __restrict__ z,
                                             const float* __restrict__ b2,
                                             float2* __restrict__ out) {
    int t = threadIdx.x;
    int v = blockIdx.x * 64 + (t >> 2);
    int lane = t & 3;
    if (v >= N_NODES) return;
    int st = startv[v], d = lenv[v];
    int nq = (d + 3) >> 2;
    const uint4* p = (const uint4*)(csr + st);
    float ax = 0.f, ay = 0.f;
    for (int j = lane; j < nq; j += 4) {
        uint4 w = p[j];
        if (w.x < N_NODES) { float2 f = z[w.x]; ax += f.x; ay += f.y; }
        if (w.y < N_NODES) { float2 f = z[w.y]; ax += f.x; ay += f.y; }
        if (w.z < N_NODES) { float2 f = z[w.z]; ax += f.x; ay += f.y; }
        if (w.w < N_NODES) { float2 f = z[w.w]; ax += f.x; ay += f.y; }
    }
    ax += __shfl_xor(ax, 1);
    ax += __shfl_xor(ax, 2);
    ay += __shfl_xor(ay, 1);
    ay += __shfl_xor(ay, 2);
    if (lane == 0) {
        float2 zz = z[v];
        float di = dinv[v];
        out[v] = make_float2(di * (ax + zz.x) + b2[0], di * (ay + zz.y) + b2[1]);
    }
}

// ---------- fallback (device atomics), used only if ws too small ----------
__global__ void f_deg(const int* __restrict__ dst, int* __restrict__ deg) {
    int i = blockIdx.x * blockDim.x + threadIdx.x;
    if (i < N_EDGES) atomicAdd(&deg[dst[i]], 1);
}
__global__ void f_node1(const float* __restrict__ x, const int* __restrict__ deg,
                        float* __restrict__ dinv, float* __restrict__ s) {
    int v = blockIdx.x * blockDim.x + threadIdx.x;
    if (v < N_NODES) {
        float di = rsqrtf((float)(deg[v] + 1));
        dinv[v] = di;
        s[v] = di * x[v];
    }
}
__global__ void f_scatter1(const int* __restrict__ src, const int* __restrict__ dst,
                           const float* __restrict__ s, float* __restrict__ agg1) {
    int i = blockIdx.x * blockDim.x + threadIdx.x;
    if (i < N_EDGES) atomicAdd(&agg1[dst[i]], s[src[i]]);
}
__global__ void f_node2(const float* __restrict__ dinv, const float* __restrict__ s,
                        const float* __restrict__ agg1, const float* __restrict__ W1,
                        const float* __restrict__ b1, const float* __restrict__ W2,
                        float2* __restrict__ z) {
    int v = blockIdx.x * blockDim.x + threadIdx.x;
    if (v < N_NODES) {
        float di = dinv[v];
        float a = di * (agg1[v] + s[v]);
        float z0 = 0.f, z1 = 0.f;
#pragma unroll
        for (int f = 0; f < 16; ++f) {
            float h = fmaxf(a * W1[f] + b1[f], 0.f);
            z0 += h * W2[2 * f + 0];
            z1 += h * W2[2 * f + 1];
        }
        z[v] = make_float2(di * z0, di * z1);
    }
}
__global__ void f_scatter2(const int* __restrict__ src, const int* __restrict__ dst,
                           const float2* __restrict__ z, float* __restrict__ agg2) {
    int i = blockIdx.x * blockDim.x + threadIdx.x;
    if (i < N_EDGES) {
        float2 zz = z[src[i]];
        int d = dst[i];
        atomicAdd(&agg2[2 * d + 0], zz.x);
        atomicAdd(&agg2[2 * d + 1], zz.y);
    }
}
__global__ void f_out(const float* __restrict__ dinv, const float2* __restrict__ z,
                      const float2* __restrict__ agg2, const float* __restrict__ b2,
                      float2* __restrict__ out) {
    int v = blockIdx.x * blockDim.x + threadIdx.x;
    if (v < N_NODES) {
        float di = dinv[v];
        float2 a = agg2[v], zz = z[v];
        out[v] = make_float2(di * (a.x + zz.x) + b2[0], di * (a.y + zz.y) + b2[1]);
    }
}

// ---------- launch ----------
extern "C" void kernel_launch(void* const* d_in, const int* in_sizes, int n_in,
                              void* d_out, int out_size, void* d_ws, size_t ws_size,
                              hipStream_t stream) {
    const float* x  = (const float*)d_in[0];
    const int* eidx = (const int*)d_in[1];
    const float* W1 = (const float*)d_in[2];
    const float* b1 = (const float*)d_in[3];
    const float* W2 = (const float*)d_in[4];
    const float* b2 = (const float*)d_in[5];
    float* out = (float*)d_out;

    const int n = N_NODES;
    const int* src = eidx;
    const int* dst = eidx + N_EDGES;

    // words layout: runinfoT | binned | csr | start | len | dinv | s | z
    size_t oRun   = 0;
    size_t oBin   = oRun + (size_t)NB * NHR;
    size_t oCsr   = oBin + (size_t)NHR * RS;
    size_t oStart = oCsr + (size_t)NB * CSRS;
    size_t oLen   = oStart + NP;
    size_t oDinv  = oLen + NP;
    size_t oS     = oDinv + NP;
    size_t oZ     = oS + NP;
    size_t need   = (oZ + 2 * NP) * sizeof(int);

    if (ws_size >= need) {
        int* wsI = (int*)d_ws;
        unsigned* runinfoT = (unsigned*)(wsI + oRun);
        unsigned* binned   = (unsigned*)(wsI + oBin);
        unsigned* csr      = (unsigned*)(wsI + oCsr);
        int* startv = wsI + oStart;
        int* lenv   = wsI + oLen;
        float* dinv = (float*)(wsI + oDinv);
        float* s    = (float*)(wsI + oS);
        float2* z   = (float2*)(wsI + oZ);

        const int gridS = (N_NODES + 63) / 64;  // 1563 blocks, 64 nodes each
        k_bin3<<<NHR, BSB, 0, stream>>>(src, dst, binned, runinfoT);
        k_regroup<<<NB, 256, 0, stream>>>(binned, runinfoT, x, csr, startv, lenv,
                                          dinv, s);
        k_s1c<<<gridS, 256, 0, stream>>>(csr, startv, lenv, dinv, s, W1, b1,
                                         W2, z);
        k_s2c<<<gridS, 256, 0, stream>>>(csr, startv, lenv, dinv, z, b2,
                                         (float2*)out);
    } else {
        float* ws = (float*)d_ws;
        int* deg    = (int*)ws;
        float* agg1 = ws + n;
        float* agg2 = ws + 2 * n;
        float* dinv = ws + 4 * n;
        float* s    = ws + 5 * n;
        float* z    = ws + 6 * n;
        (void)hipMemsetAsync(d_ws, 0, (size_t)(4 * n) * sizeof(float), stream);
        const int gridE = (N_EDGES + 255) / 256;
        const int gridN = (n + 255) / 256;
        f_deg<<<gridE, 256, 0, stream>>>(dst, deg);
        f_node1<<<gridN, 256, 0, stream>>>(x, deg, dinv, s);
        f_scatter1<<<gridE, 256, 0, stream>>>(src, dst, s, agg1);
        f_node2<<<gridN, 256, 0, stream>>>(dinv, s, agg1, W1, b1, W2, (float2*)z);
        f_scatter2<<<gridE, 256, 0, stream>>>(src, dst, (const float2*)z, agg2);
        f_out<<<gridN, 256, 0, stream>>>(dinv, (const float2*)z, (const float2*)agg2,
                                         b2, (float2*)out);
    }
}

// Round 21
// 78.798 us; speedup vs baseline: 1.0228x; 1.0228x over previous
//
#include <hip/hip_runtime.h>

#define N_NODES 100000
#define NP 100096            // NB*128 padded node count
#define N_EDGES 3200000
#define NB 782               // buckets of 128 nodes
#define NBP 1024             // padded bins for scan
#define NHR 256              // binning blocks / regions (256*12500 = 3.2M exact)
#define EPB (N_EDGES / NHR)  // 12500 edges per region (mult of 4)
#define RS 14848             // region stride (words): 12500 + 3*782 = 14846 max
#define BSB 1024             // binning block threads (1 bin/thread in scan)
#define CAP 6144             // regroup stage capacity (padded words)
#define CAPO 5120            // regroup out capacity (quad-padded per-node segs)
#define CSRS 5120            // csr words per bucket (mult of 4)
#define SENT 128u            // run-pad sentinel: low byte 128

typedef unsigned char u8;

// ---------- binning: register-staged edges, LDS counting sort, linear flush ----
// binned region-major; runs 4-word aligned; pads hold SENT.
// packed = (src<<8)|(dst&127). runinfoT[b*NHR+r] = off | (nq<<16), nq quads.
__global__ __launch_bounds__(BSB) void k_bin3(const int* __restrict__ src,
                                              const int* __restrict__ dst,
                                              unsigned* __restrict__ binned,
                                              unsigned* __restrict__ runinfoT) {
    __shared__ int hist[NBP];
    __shared__ int scanv[NBP];
    __shared__ int sh[BSB];
    __shared__ alignas(16) unsigned stage[RS];
    int t = threadIdx.x, blk = blockIdx.x;
    for (int i = t; i < NBP; i += BSB) hist[i] = 0;
    for (int i = t; i < RS; i += BSB) stage[i] = SENT;
    __syncthreads();
    int base = blk * EPB;
    // load src/dst quads ONCE into registers; feed histogram from regs
    int4 dreg[4], sreg[4];
    bool valid[4];
#pragma unroll
    for (int k = 0; k < 4; ++k) {
        int q = t + k * BSB;          // quad index; EPB/4 = 3125 quads
        valid[k] = (q * 4 < EPB);
        if (valid[k]) {
            dreg[k] = *(const int4*)(dst + base + q * 4);
            sreg[k] = *(const int4*)(src + base + q * 4);
            atomicAdd(&hist[dreg[k].x >> 7], 1);
            atomicAdd(&hist[dreg[k].y >> 7], 1);
            atomicAdd(&hist[dreg[k].z >> 7], 1);
            atomicAdd(&hist[dreg[k].w >> 7], 1);
        }
    }
    __syncthreads();
    // quad-padded exclusive scan, 1 bin per thread (NBP == BSB)
    int c = hist[t];
    int pc = (c + 3) & ~3;
    sh[t] = pc;
    __syncthreads();
    for (int off = 1; off < BSB; off <<= 1) {
        int u = (t >= off) ? sh[t - off] : 0;
        __syncthreads();
        sh[t] += u;
        __syncthreads();
    }
    int excl = sh[t] - pc;
    scanv[t] = excl;
    __syncthreads();
    int padTot = sh[BSB - 1];
    if (t < NB)
        runinfoT[(size_t)t * NHR + blk] =
            (unsigned)excl | ((unsigned)((c + 3) >> 2) << 16);
    __syncthreads();
    // scatter from registers; scanv doubles as cursor
#pragma unroll
    for (int k = 0; k < 4; ++k) {
        if (valid[k]) {
            int p;
            p = atomicAdd(&scanv[dreg[k].x >> 7], 1);
            stage[p] = ((unsigned)sreg[k].x << 8) | (unsigned)(dreg[k].x & 127);
            p = atomicAdd(&scanv[dreg[k].y >> 7], 1);
            stage[p] = ((unsigned)sreg[k].y << 8) | (unsigned)(dreg[k].y & 127);
            p = atomicAdd(&scanv[dreg[k].z >> 7], 1);
            stage[p] = ((unsigned)sreg[k].z << 8) | (unsigned)(dreg[k].z & 127);
            p = atomicAdd(&scanv[dreg[k].w >> 7], 1);
            stage[p] = ((unsigned)sreg[k].w << 8) | (unsigned)(dreg[k].w & 127);
        }
    }
    __syncthreads();
    for (int i = t * 4; i < padTot; i += BSB * 4)
        *(int4*)(binned + (size_t)blk * RS + i) = *(const int4*)(stage + i);
}

// ---------- regroup: bucket -> per-node QUAD-ALIGNED CSR + degree + node1 ------
// (round-19 v1 structure — measured best)
__global__ __launch_bounds__(256) void k_regroup(
        const unsigned* __restrict__ binned, const unsigned* __restrict__ runinfoT,
        const float* __restrict__ x, unsigned* __restrict__ csr,
        int* __restrict__ startv, int* __restrict__ lenv,
        float* __restrict__ dinv, float* __restrict__ s) {
    __shared__ unsigned rinfo[NHR];
    __shared__ int pref[NHR];
    __shared__ int sh[256];
    __shared__ alignas(16) unsigned stage[CAP];
    __shared__ unsigned outA[CAPO];
    __shared__ int cnt[128];
    __shared__ int excl4[128];
    __shared__ int cur[128];
    int t = threadIdx.x, b = blockIdx.x;
    rinfo[t] = runinfoT[(size_t)b * NHR + t];  // NHR == 256 == blockDim
    if (t < 128) cnt[t] = 0;
    for (int i = t; i < CAPO; i += 256) outA[i] = 0xFFFFFFFFu;
    __syncthreads();
    int vv = 4 * (int)(rinfo[t] >> 16);
    sh[t] = vv;
    __syncthreads();
    for (int off = 1; off < 256; off <<= 1) {
        int u = (t >= off) ? sh[t - off] : 0;
        __syncthreads();
        sh[t] += u;
        __syncthreads();
    }
    pref[t] = sh[t] - vv;
    __syncthreads();
    int padTot = sh[255];
    int g = t >> 2, lane = t & 3;
    for (int r = g; r < NHR; r += 64) {
        unsigned ri = rinfo[r];
        int off = (int)(ri & 0xFFFFu), nq = (int)(ri >> 16);
        int bs = pref[r];
        if (bs + 4 * nq > CAP) continue;  // impossible-margin guard
        const uint4* p = (const uint4*)(binned + (size_t)r * RS + off);
        for (int j = lane; j < nq; j += 4) {
            uint4 w = p[j];
            *(uint4*)(&stage[bs + 4 * j]) = make_uint4(w.x, w.y, w.z, w.w);
        }
    }
    __syncthreads();
    for (int i = t; i < padTot; i += 256) {
        unsigned w = stage[i];
        if ((w & 255u) != 128u) atomicAdd(&cnt[w & 127], 1);
    }
    __syncthreads();
    if (t < 128) sh[t] = (cnt[t] + 3) & ~3;
    __syncthreads();
    for (int off = 1; off < 128; off <<= 1) {
        int u = (t >= off && t < 128) ? sh[t - off] : 0;
        __syncthreads();
        if (t < 128) sh[t] += u;
        __syncthreads();
    }
    if (t < 128) {
        int pc = (cnt[t] + 3) & ~3;
        excl4[t] = sh[t] - pc;
        cur[t] = sh[t] - pc;
    }
    __syncthreads();
    for (int i = t; i < padTot; i += 256) {
        unsigned w = stage[i];
        if ((w & 255u) != 128u) {
            int pos = atomicAdd(&cur[w & 127], 1);
            if (pos < CAPO) outA[pos] = w >> 8;
        }
    }
    __syncthreads();
    int fillTot = excl4[127] + ((cnt[127] + 3) & ~3);
    if (fillTot > CAPO) fillTot = CAPO;
    for (int i = t; i < fillTot; i += 256)
        csr[(size_t)b * CSRS + i] = outA[i];
    if (t < 128) {
        int node = b * 128 + t;
        if (node < N_NODES) {
            int d = cnt[t];
            float di = rsqrtf((float)(d + 1));  // +1 self-loop
            dinv[node] = di;
            s[node] = di * x[node];
            startv[node] = b * CSRS + excl4[t];  // quad-aligned
            lenv[node] = d;
        }
    }
}

// ---------- s1 + MLP fused: 4-lane group per node, uint4 coalesced CSR ----------
__global__ __launch_bounds__(256) void k_s1c(const unsigned* __restrict__ csr,
                                             const int* __restrict__ startv,
                                             const int* __restrict__ lenv,
                                             const float* __restrict__ dinv,
                                             const float* __restrict__ s,
                                             const float* __restrict__ W1,
                                             const float* __restrict__ b1,
                                             const float* __restrict__ W2,
                                             float2* __restrict__ z) {
    int t = threadIdx.x;
    int v = blockIdx.x * 64 + (t >> 2);
    int lane = t & 3;
    if (v >= N_NODES) return;
    int st = startv[v], d = lenv[v];
    int nq = (d + 3) >> 2;
    const uint4* p = (const uint4*)(csr + st);
    float acc = 0.f;
    for (int j = lane; j < nq; j += 4) {
        uint4 w = p[j];
        float f0 = (w.x < N_NODES) ? s[w.x] : 0.f;
        float f1 = (w.y < N_NODES) ? s[w.y] : 0.f;
        float f2 = (w.z < N_NODES) ? s[w.z] : 0.f;
        float f3 = (w.w < N_NODES) ? s[w.w] : 0.f;
        acc += (f0 + f1) + (f2 + f3);
    }
    acc += __shfl_xor(acc, 1);
    acc += __shfl_xor(acc, 2);
    if (lane == 0) {
        float di = dinv[v];
        float a = di * (acc + s[v]);  // self-loop term
        float z0 = 0.f, z1 = 0.f;
#pragma unroll
        for (int f = 0; f < 16; ++f) {
            float h = fmaxf(a * W1[f] + b1[f], 0.f);
            z0 += h * W2[2 * f + 0];
            z1 += h * W2[2 * f + 1];
        }
        z[v] = make_float2(di * z0, di * z1);
    }
}

// ---------- s2 + epilogue fused: 4-lane group per node, float2 gathers ----------
__global__ __launch_bounds__(256) void k_s2c(const unsigned* __restrict__ csr,
                                             const int* __restrict__ startv,
                                             const int* __restrict__ lenv,
                                             const float* __restrict__ dinv,
                                             const float2* __restrict__ z,
                                             const float* __restrict__ b2,
                                             float2* __restrict__ out) {
    int t = threadIdx.x;
    int v = blockIdx.x * 64 + (t >> 2);
    int lane = t & 3;
    if (v >= N_NODES) return;
    int st = startv[v], d = lenv[v];
    int nq = (d + 3) >> 2;
    const uint4* p = (const uint4*)(csr + st);
    float ax = 0.f, ay = 0.f;
    for (int j = lane; j < nq; j += 4) {
        uint4 w = p[j];
        if (w.x < N_NODES) { float2 f = z[w.x]; ax += f.x; ay += f.y; }
        if (w.y < N_NODES) { float2 f = z[w.y]; ax += f.x; ay += f.y; }
        if (w.z < N_NODES) { float2 f = z[w.z]; ax += f.x; ay += f.y; }
        if (w.w < N_NODES) { float2 f = z[w.w]; ax += f.x; ay += f.y; }
    }
    ax += __shfl_xor(ax, 1);
    ax += __shfl_xor(ax, 2);
    ay += __shfl_xor(ay, 1);
    ay += __shfl_xor(ay, 2);
    if (lane == 0) {
        float2 zz = z[v];
        float di = dinv[v];
        out[v] = make_float2(di * (ax + zz.x) + b2[0], di * (ay + zz.y) + b2[1]);
    }
}

// ---------- fallback (device atomics), used only if ws too small ----------
__global__ void f_deg(const int* __restrict__ dst, int* __restrict__ deg) {
    int i = blockIdx.x * blockDim.x + threadIdx.x;
    if (i < N_EDGES) atomicAdd(&deg[dst[i]], 1);
}
__global__ void f_node1(const float* __restrict__ x, const int* __restrict__ deg,
                        float* __restrict__ dinv, float* __restrict__ s) {
    int v = blockIdx.x * blockDim.x + threadIdx.x;
    if (v < N_NODES) {
        float di = rsqrtf((float)(deg[v] + 1));
        dinv[v] = di;
        s[v] = di * x[v];
    }
}
__global__ void f_scatter1(const int* __restrict__ src, const int* __restrict__ dst,
                           const float* __restrict__ s, float* __restrict__ agg1) {
    int i = blockIdx.x * blockDim.x + threadIdx.x;
    if (i < N_EDGES) atomicAdd(&agg1[dst[i]], s[src[i]]);
}
__global__ void f_node2(const float* __restrict__ dinv, const float* __restrict__ s,
                        const float* __restrict__ agg1, const float* __restrict__ W1,
                        const float* __restrict__ b1, const float* __restrict__ W2,
                        float2* __restrict__ z) {
    int v = blockIdx.x * blockDim.x + threadIdx.x;
    if (v < N_NODES) {
        float di = dinv[v];
        float a = di * (agg1[v] + s[v]);
        float z0 = 0.f, z1 = 0.f;
#pragma unroll
        for (int f = 0; f < 16; ++f) {
            float h = fmaxf(a * W1[f] + b1[f], 0.f);
            z0 += h * W2[2 * f + 0];
            z1 += h * W2[2 * f + 1];
        }
        z[v] = make_float2(di * z0, di * z1);
    }
}
__global__ void f_scatter2(const int* __restrict__ src, const int* __restrict__ dst,
                           const float2* __restrict__ z, float* __restrict__ agg2) {
    int i = blockIdx.x * blockDim.x + threadIdx.x;
    if (i < N_EDGES) {
        float2 zz = z[src[i]];
        int d = dst[i];
        atomicAdd(&agg2[2 * d + 0], zz.x);
        atomicAdd(&agg2[2 * d + 1], zz.y);
    }
}
__global__ void f_out(const float* __restrict__ dinv, const float2* __restrict__ z,
                      const float2* __restrict__ agg2, const float* __restrict__ b2,
                      float2* __restrict__ out) {
    int v = blockIdx.x * blockDim.x + threadIdx.x;
    if (v < N_NODES) {
        float di = dinv[v];
        float2 a = agg2[v], zz = z[v];
        out[v] = make_float2(di * (a.x + zz.x) + b2[0], di * (a.y + zz.y) + b2[1]);
    }
}

// ---------- launch ----------
extern "C" void kernel_launch(void* const* d_in, const int* in_sizes, int n_in,
                              void* d_out, int out_size, void* d_ws, size_t ws_size,
                              hipStream_t stream) {
    const float* x  = (const float*)d_in[0];
    const int* eidx = (const int*)d_in[1];
    const float* W1 = (const float*)d_in[2];
    const float* b1 = (const float*)d_in[3];
    const float* W2 = (const float*)d_in[4];
    const float* b2 = (const float*)d_in[5];
    float* out = (float*)d_out;

    const int n = N_NODES;
    const int* src = eidx;
    const int* dst = eidx + N_EDGES;

    // words layout: runinfoT | binned | csr | start | len | dinv | s | z
    size_t oRun   = 0;
    size_t oBin   = oRun + (size_t)NB * NHR;
    size_t oCsr   = oBin + (size_t)NHR * RS;
    size_t oStart = oCsr + (size_t)NB * CSRS;
    size_t oLen   = oStart + NP;
    size_t oDinv  = oLen + NP;
    size_t oS     = oDinv + NP;
    size_t oZ     = oS + NP;
    size_t need   = (oZ + 2 * NP) * sizeof(int);

    if (ws_size >= need) {
        int* wsI = (int*)d_ws;
        unsigned* runinfoT = (unsigned*)(wsI + oRun);
        unsigned* binned   = (unsigned*)(wsI + oBin);
        unsigned* csr      = (unsigned*)(wsI + oCsr);
        int* startv = wsI + oStart;
        int* lenv   = wsI + oLen;
        float* dinv = (float*)(wsI + oDinv);
        float* s    = (float*)(wsI + oS);
        float2* z   = (float2*)(wsI + oZ);

        const int gridS = (N_NODES + 63) / 64;  // 1563 blocks, 64 nodes each
        k_bin3<<<NHR, BSB, 0, stream>>>(src, dst, binned, runinfoT);
        k_regroup<<<NB, 256, 0, stream>>>(binned, runinfoT, x, csr, startv, lenv,
                                          dinv, s);
        k_s1c<<<gridS, 256, 0, stream>>>(csr, startv, lenv, dinv, s, W1, b1,
                                         W2, z);
        k_s2c<<<gridS, 256, 0, stream>>>(csr, startv, lenv, dinv, z, b2,
                                         (float2*)out);
    } else {
        float* ws = (float*)d_ws;
        int* deg    = (int*)ws;
        float* agg1 = ws + n;
        float* agg2 = ws + 2 * n;
        float* dinv = ws + 4 * n;
        float* s    = ws + 5 * n;
        float* z    = ws + 6 * n;
        (void)hipMemsetAsync(d_ws, 0, (size_t)(4 * n) * sizeof(float), stream);
        const int gridE = (N_EDGES + 255) / 256;
        const int gridN = (n + 255) / 256;
        f_deg<<<gridE, 256, 0, stream>>>(dst, deg);
        f_node1<<<gridN, 256, 0, stream>>>(x, deg, dinv, s);
        f_scatter1<<<gridE, 256, 0, stream>>>(src, dst, s, agg1);
        f_node2<<<gridN, 256, 0, stream>>>(dinv, s, agg1, W1, b1, W2, (float2*)z);
        f_scatter2<<<gridE, 256, 0, stream>>>(src, dst, (const float2*)z, agg2);
        f_out<<<gridN, 256, 0, stream>>>(dinv, (const float2*)z, (const float2*)agg2,
                                         b2, (float2*)out);
    }
}